// Round 5
// baseline (344.601 us; speedup 1.0000x reference)
//
#include <hip/hip_runtime.h>

// ---------------------------------------------------------------------------
// Attention (GQA + RoPE + softcap + causal) on gfx950, bf16 MFMA pipeline.
// B=2 T=2048 D=2048, NH=16 NKV=8 HD=128, softcap=50, causal.
// R5: flash v4 — 2x2 fragment split (wave = 32 Q-rows x 32 keys): K-frag and
//     V-frag LDS reads halved (flash is LDS-read-bound: 504 -> ~315 cy per
//     wave-tile). PV is partial-K over the wave's own keys (sP stays
//     wave-private, no extra per-tile barrier); O pairs merged once at end
//     through the dead sK/sVt LDS. GEMMs/prep unchanged from R4.
// ---------------------------------------------------------------------------

typedef unsigned short u16;
typedef __attribute__((ext_vector_type(8))) short short8;   // 8 x bf16 (4 VGPRs)
typedef __attribute__((ext_vector_type(4))) float floatx4;  // MFMA acc

static __device__ __forceinline__ u16 f2b(float f){
  unsigned u = __float_as_uint(f);
  u = (u + 0x7fffu + ((u >> 16) & 1u)) >> 16;   // RNE
  return (u16)u;
}
static __device__ __forceinline__ float b2f(u16 u){
  return __uint_as_float(((unsigned)u) << 16);
}
// async global->LDS DMA, 16B per lane; LDS dest = wave-uniform base + lane*16
static __device__ __forceinline__ void gload16(const u16* g, u16* l){
  __builtin_amdgcn_global_load_lds(
      (const __attribute__((address_space(1))) unsigned int*)g,
      (__attribute__((address_space(3))) unsigned int*)l, 16, 0, 0);
}

// ---- prep: x->bf16 | w_q/w_kv/w_out transpose->B^T bf16 | sin/cos table ----
static __device__ void tr64(const float* __restrict__ s, u16* __restrict__ d,
                            int sRS, int dRS, float (*t)[65], int tid){
  #pragma unroll
  for(int i = 0; i < 16; i++){
    int idx = tid + 256 * i;
    t[idx >> 6][idx & 63] = s[(long)(idx >> 6) * sRS + (idx & 63)];
  }
  __syncthreads();
  #pragma unroll
  for(int i = 0; i < 16; i++){
    int idx = tid + 256 * i;
    d[(long)(idx >> 6) * dRS + (idx & 63)] = f2b(t[idx & 63][idx >> 6]);
  }
}

__global__ __launch_bounds__(256) void k_prep(
    const float* __restrict__ x, u16* __restrict__ xb,
    const float* __restrict__ wq, u16* __restrict__ wq_t,
    const float* __restrict__ wkv, u16* __restrict__ wkv_t,
    const float* __restrict__ wo, u16* __restrict__ wo_t,
    const int* __restrict__ pos, float* __restrict__ tab){
  __shared__ float t[64][65];
  int blk = blockIdx.x, tid = threadIdx.x;
  if(blk < 8192){                               // x fp32 -> bf16
    int i = blk * 256 + tid;
    float4 v = ((const float4*)x)[i];
    ushort4 o = make_ushort4(f2b(v.x), f2b(v.y), f2b(v.z), f2b(v.w));
    ((ushort4*)xb)[i] = o;
  } else if(blk < 9216){                        // w_q [16][2048][128] -> [16][128][2048]
    int q = blk - 8192;
    int bx = q & 1, by = (q >> 1) & 31, bz = q >> 6;
    tr64(wq + (long)bz * 262144 + (long)by * 64 * 128 + bx * 64,
         wq_t + (long)bz * 262144 + (long)bx * 64 * 2048 + by * 64, 128, 2048, t, tid);
  } else if(blk < 10240){                       // w_kv [16][2048][128] -> [16][128][2048]
    int q = blk - 9216;
    int bx = q & 1, by = (q >> 1) & 31, bz = q >> 6;
    tr64(wkv + (long)bz * 262144 + (long)by * 64 * 128 + bx * 64,
         wkv_t + (long)bz * 262144 + (long)bx * 64 * 2048 + by * 64, 128, 2048, t, tid);
  } else if(blk < 11264){                       // w_out [2048][2048] -> transpose
    int q = blk - 10240;
    int bx = q & 31, by = q >> 5;
    tr64(wo + (long)by * 64 * 2048 + bx * 64,
         wo_t + (long)bx * 64 * 2048 + by * 64, 2048, 2048, t, tid);
  } else {                                      // sin/cos: tab[row][0:64]=sin, [64:128]=cos
    int idx = (blk - 11264) * 256 + tid;        // 262,144 = 4096 rows x 64 h
    int row = idx >> 6, h = idx & 63;
    float pf = (float)pos[row];
    float inv = exp2f(-0.20762050593045077f * (float)h);  // 10000^(-h/64)
    float ang = pf * inv;
    tab[(row << 7) + h]      = sinf(ang);
    tab[(row << 7) + 64 + h] = cosf(ang);
  }
}

// ---- fused QKV projection GEMM + RoPE + V-transpose epilogue ---------------
// nt<16 -> q head nt ; 16..23 -> k head nt-16 ; 24..31 -> v head nt-24.
__global__ __launch_bounds__(256) void k_gemm_qkv(
    const u16* __restrict__ A, const u16* __restrict__ wq_t, const u16* __restrict__ wkv_t,
    const float* __restrict__ tab,
    u16* __restrict__ qb, u16* __restrict__ kb, u16* __restrict__ vtp){
  __shared__ __attribute__((aligned(16))) u16 pool[128 * 132]; // staging 32KB | epi tile
  u16* sA = pool;                               // [128][64]
  u16* sB = pool + 8192;                        // [128][64]
  int mt = blockIdx.x, nt = blockIdx.y;
  const u16* Bt = (nt < 16) ? (wq_t + (long)nt * 262144)
                            : (wkv_t + (long)(nt - 16) * 262144);
  int tid = threadIdx.x;
  int lane = tid & 63, wave = tid >> 6, l15 = lane & 15, quad = lane >> 4;
  int ro = (wave & 1) * 64, co = (wave >> 1) * 64;
  int xm7 = l15 & 7;
  int srow = tid >> 3;
  int gch  = (tid & 7) ^ (srow & 7);            // XOR-swizzled staging chunks
  const u16* Ag = A  + ((long)(mt * 128) + srow) * 2048 + (gch << 3);
  const u16* Bg = Bt + (long)srow * 2048 + (gch << 3);
  u16* lA = sA + tid * 8;
  u16* lB = sB + tid * 8;
  floatx4 acc[4][4];
  const floatx4 fz = {0.f, 0.f, 0.f, 0.f};
  #pragma unroll
  for(int r = 0; r < 4; r++)
    #pragma unroll
    for(int c = 0; c < 4; c++) acc[r][c] = fz;
  for(int k0 = 0; k0 < 2048; k0 += 64){
    #pragma unroll
    for(int r = 0; r < 4; r++){
      gload16(Ag + (long)r * 65536 + k0, lA + r * 2048);
      gload16(Bg + (long)r * 65536 + k0, lB + r * 2048);
    }
    __syncthreads();
    #pragma unroll
    for(int ks = 0; ks < 2; ks++){
      short8 af[4], bfr[4];
      #pragma unroll
      for(int r = 0; r < 4; r++)
        af[r]  = *(const short8*)(sA + ((ro + r * 16 + l15) << 6) + ((((ks << 2) | quad) ^ xm7) << 3));
      #pragma unroll
      for(int c = 0; c < 4; c++)
        bfr[c] = *(const short8*)(sB + ((co + c * 16 + l15) << 6) + ((((ks << 2) | quad) ^ xm7) << 3));
      #pragma unroll
      for(int r = 0; r < 4; r++)
        #pragma unroll
        for(int c = 0; c < 4; c++)
          acc[r][c] = __builtin_amdgcn_mfma_f32_16x16x32_bf16(af[r], bfr[c], acc[r][c], 0, 0, 0);
    }
    __syncthreads();
  }
  // ---- epilogue: stash tile (bf16) into sT[128][132], then rope / v-transpose
  u16* sT = pool;
  #pragma unroll
  for(int r = 0; r < 4; r++)
    #pragma unroll
    for(int c = 0; c < 4; c++){
      int row = ro + r * 16 + quad * 4, col = co + c * 16 + l15;
      #pragma unroll
      for(int j = 0; j < 4; j++) sT[(row + j) * 132 + col] = f2b(acc[r][c][j]);
    }
  __syncthreads();
  int grow0 = mt * 128;
  if(nt < 24){                                  // q or k: rope(+scale) -> qb/kb
    float scale = (nt < 16) ? 0.08838834764831845f : 1.0f;
    u16* dst = (nt < 16) ? qb : kb;
    int dS   = (nt < 16) ? 2048 : 1024;
    int dcol = (nt < 16) ? nt * 128 : (nt - 16) * 128;
    #pragma unroll
    for(int it = 0; it < 16; it++){
      int idx = tid + 256 * it;                 // 4096 u32 pair-words
      int row = idx >> 5, cw = idx & 31;        // h pair = {2cw, 2cw+1}
      int grow = grow0 + row;
      unsigned lo = *(const unsigned*)&sT[row * 132 + 2 * cw];
      unsigned hi = *(const unsigned*)&sT[row * 132 + 64 + 2 * cw];
      float2 sn = *(const float2*)&tab[(grow << 7) + 2 * cw];
      float2 cs = *(const float2*)&tab[(grow << 7) + 64 + 2 * cw];
      float x1a = b2f((u16)lo), x1b = b2f((u16)(lo >> 16));
      float x2a = b2f((u16)hi), x2b = b2f((u16)(hi >> 16));
      float o1a = (x1a * cs.x - x2a * sn.x) * scale;
      float o1b = (x1b * cs.y - x2b * sn.y) * scale;
      float o2a = (x2a * cs.x + x1a * sn.x) * scale;
      float o2b = (x2b * cs.y + x1b * sn.y) * scale;
      unsigned w1 = (unsigned)f2b(o1a) | ((unsigned)f2b(o1b) << 16);
      unsigned w2 = (unsigned)f2b(o2a) | ((unsigned)f2b(o2b) << 16);
      *(unsigned*)&dst[(long)grow * dS + dcol + 2 * cw] = w1;
      *(unsigned*)&dst[(long)grow * dS + dcol + 64 + 2 * cw] = w2;
    }
  } else {                                      // v: transposed -> v_t[b][kv][h][s]
    int b = mt >> 4, kvh = nt - 24;
    u16* vt = vtp + (long)(b * 8 + kvh) * 262144;
    int tcol0 = (mt & 15) * 128;
    int h = tid >> 1, s0 = (tid & 1) * 64;
    #pragma unroll
    for(int i = 0; i < 16; i++){
      int s = s0 + i * 4;
      ushort4 v4 = make_ushort4(sT[(s    ) * 132 + h], sT[(s + 1) * 132 + h],
                                sT[(s + 2) * 132 + h], sT[(s + 3) * 132 + h]);
      *(ushort4*)&vt[(long)h * 2048 + tcol0 + s] = v4;
    }
  }
}

// ---- out projection GEMM: enc[4096x2048] x w_out^T -> fp32 out -------------
__global__ __launch_bounds__(256) void k_gemm_out(
    const u16* __restrict__ A, const u16* __restrict__ Bt0, float* __restrict__ C){
  __shared__ __attribute__((aligned(16))) u16 sA[128 * 64];
  __shared__ __attribute__((aligned(16))) u16 sB[128 * 64];
  int mt = blockIdx.x, nt = blockIdx.y;
  const u16* Bt = Bt0 + (long)nt * 262144;
  int tid = threadIdx.x;
  int lane = tid & 63, wave = tid >> 6, l15 = lane & 15, quad = lane >> 4;
  int ro = (wave & 1) * 64, co = (wave >> 1) * 64;
  int xm7 = l15 & 7;
  int srow = tid >> 3;
  int gch  = (tid & 7) ^ (srow & 7);
  const u16* Ag = A  + ((long)(mt * 128) + srow) * 2048 + (gch << 3);
  const u16* Bg = Bt + (long)srow * 2048 + (gch << 3);
  u16* lA = sA + tid * 8;
  u16* lB = sB + tid * 8;
  floatx4 acc[4][4];
  const floatx4 fz = {0.f, 0.f, 0.f, 0.f};
  #pragma unroll
  for(int r = 0; r < 4; r++)
    #pragma unroll
    for(int c = 0; c < 4; c++) acc[r][c] = fz;
  for(int k0 = 0; k0 < 2048; k0 += 64){
    #pragma unroll
    for(int r = 0; r < 4; r++){
      gload16(Ag + (long)r * 65536 + k0, lA + r * 2048);
      gload16(Bg + (long)r * 65536 + k0, lB + r * 2048);
    }
    __syncthreads();
    #pragma unroll
    for(int ks = 0; ks < 2; ks++){
      short8 af[4], bfr[4];
      #pragma unroll
      for(int r = 0; r < 4; r++)
        af[r]  = *(const short8*)(sA + ((ro + r * 16 + l15) << 6) + ((((ks << 2) | quad) ^ xm7) << 3));
      #pragma unroll
      for(int c = 0; c < 4; c++)
        bfr[c] = *(const short8*)(sB + ((co + c * 16 + l15) << 6) + ((((ks << 2) | quad) ^ xm7) << 3));
      #pragma unroll
      for(int r = 0; r < 4; r++)
        #pragma unroll
        for(int c = 0; c < 4; c++)
          acc[r][c] = __builtin_amdgcn_mfma_f32_16x16x32_bf16(af[r], bfr[c], acc[r][c], 0, 0, 0);
    }
    __syncthreads();
  }
  long rb0 = (long)mt * 128 + ro + quad * 4;
  #pragma unroll
  for(int r = 0; r < 4; r++)
    #pragma unroll
    for(int c = 0; c < 4; c++){
      int col = nt * 128 + co + c * 16 + l15;
      #pragma unroll
      for(int j = 0; j < 4; j++)
        C[(rb0 + r * 16 + j) * 2048 + col] = acc[r][c][j];
    }
}

// ---- flash attention v4 ----------------------------------------------------
// Q-tile 64, K-tile 64, causal, fixed-max softmax (softcap bounds z to
// [-50,50] so p=e^z is safe). 2x2 wave split: wave (rq,kq) computes
// S[rq*32..+31][kq*32..+31]; PV is partial-K over the wave's own 32 keys
// (sP wave-private, chunk^row swizzle); O halves pair-merged at end via LDS.
// K/V double-buffered global_load_lds DMA, one barrier per tile.
__global__ __launch_bounds__(256) void k_flash(
    const u16* __restrict__ qb, const u16* __restrict__ kb,
    const u16* __restrict__ vt, u16* __restrict__ enc){
  __shared__ __attribute__((aligned(16))) u16 sK[2 * 64 * 128];   // 32 KB
  __shared__ __attribute__((aligned(16))) u16 sVt[2 * 128 * 64];  // 32 KB
  __shared__ __attribute__((aligned(16))) u16 sP[4][32][40];      // 10 KB
  int qt = 31 - blockIdx.y;                    // longest blocks dispatch first
  int hidx = blockIdx.x;
  int b = hidx >> 4, kv = (hidx >> 1) & 7, g = hidx & 1;
  int tid = threadIdx.x;
  int lane = tid & 63, wave = tid >> 6, l15 = lane & 15, quad = lane >> 4;
  int rq = wave >> 1, kq = wave & 1;           // Q-row half / key half

  // Q fragments, rows rq*32 + rf*16 + l15 (A-layout)
  short8 qf[2][4];
  {
    const u16* qg = qb + ((long)b * 2048 + qt * 64 + rq * 32 + l15) * 2048
                       + (kv * 2 + g) * 128 + quad * 8;
    #pragma unroll
    for(int rf = 0; rf < 2; rf++)
      #pragma unroll
      for(int ks = 0; ks < 4; ks++)
        qf[rf][ks] = *(const short8*)(qg + rf * 16 * 2048 + ks * 32);
  }

  // DMA staging (identical to v3.1): K rows 256B/16 chunks ^row&15; Vt 128B/8 ^row&7
  int krow = tid >> 4;
  int kch  = (tid & 15) ^ krow;
  const u16* Kg = kb + ((long)b * 2048 + krow) * 1024 + kv * 128 + (kch << 3);
  int vrow = tid >> 3;
  int vch  = (tid & 7) ^ (vrow & 7);
  const u16* Vg = vt + ((long)(b * 8 + kv) * 128 + vrow) * 2048 + (vch << 3);
  u16* lK = sK  + tid * 8;
  u16* lV = sVt + tid * 8;
  #pragma unroll
  for(int r = 0; r < 4; r++){                   // preload tile 0 -> buf 0
    gload16(Kg + (long)r * 16384, lK + r * 2048);
    gload16(Vg + (long)r * 65536, lV + r * 2048);
  }

  float l_loc[2][4] = {{0.f,0.f,0.f,0.f},{0.f,0.f,0.f,0.f}};
  floatx4 o_acc[2][8];                          // rows rf*16+quad*4+r, cols cf*16+l15
  const floatx4 fz = {0.f, 0.f, 0.f, 0.f};
  #pragma unroll
  for(int rf = 0; rf < 2; rf++)
    #pragma unroll
    for(int c = 0; c < 8; c++) o_acc[rf][c] = fz;

  const float c1 = 0.057707801635558536f;      // 2*log2(e)/50
  const float c2 = -144.26950408889634f;       // -100*log2(e)
  const float c3 = 72.13475204444817f;         // 50*log2(e)

  for(int kt = 0; kt <= qt; kt++){
    int buf = (kt & 1) * 8192;
    __syncthreads();                           // DMA(kt) drained; buf^1 free
    if(kt < qt){                               // async stage tile kt+1
      int nb = buf ^ 8192;
      #pragma unroll
      for(int r = 0; r < 4; r++){
        gload16(Kg + (long)(kt + 1) * 65536 + (long)r * 16384, lK + nb + r * 2048);
        gload16(Vg + (kt + 1) * 64 + (long)r * 65536, lV + nb + r * 2048);
      }
    }
    // S = Q K^T : rows rq*32+rf*16, keys kq*32+cf*16 (bk reused across rf)
    floatx4 s_acc[2][2];
    #pragma unroll
    for(int rf = 0; rf < 2; rf++)
      #pragma unroll
      for(int cf = 0; cf < 2; cf++) s_acc[rf][cf] = fz;
    #pragma unroll
    for(int ks = 0; ks < 4; ks++){
      #pragma unroll
      for(int cf = 0; cf < 2; cf++){
        int row = kq * 32 + cf * 16 + l15;     // row&15 == l15
        short8 bk = *(const short8*)(sK + buf + (row << 7)
                                     + ((((ks << 2) | quad) ^ l15) << 3));
        #pragma unroll
        for(int rf = 0; rf < 2; rf++)
          s_acc[rf][cf] = __builtin_amdgcn_mfma_f32_16x16x32_bf16(qf[rf][ks], bk, s_acc[rf][cf], 0, 0, 0);
      }
    }
    // softcap: p = exp2(c2/(u+1)+c3), u = exp2(c1*s); write wave-private sP
    bool diag = (kt == qt);
    #pragma unroll
    for(int rf = 0; rf < 2; rf++)
      #pragma unroll
      for(int cf = 0; cf < 2; cf++)
        #pragma unroll
        for(int r = 0; r < 4; r++){
          float s = s_acc[rf][cf][r];
          float u = __builtin_amdgcn_exp2f(c1 * s);
          float d = __builtin_amdgcn_rcpf(u + 1.f);
          float p = __builtin_amdgcn_exp2f(__builtin_fmaf(c2, d, c3));
          if(diag && (kq * 32 + cf * 16 + l15 > rq * 32 + rf * 16 + quad * 4 + r)) p = 0.f;
          l_loc[rf][r] += p;
          int chunk = ((cf << 1) | (l15 >> 3)) ^ r;   // row_local&3 == r
          sP[wave][rf * 16 + quad * 4 + r][(chunk << 3) + (l15 & 7)] = f2b(p);
        }
    // O += P[:, own 32 keys] * V[own 32 keys, :]  (one K=32 MFMA step)
    #pragma unroll
    for(int rf = 0; rf < 2; rf++){
      short8 ap = *(const short8*)&sP[wave][rf * 16 + l15][(quad ^ (l15 & 3)) << 3];
      #pragma unroll
      for(int cf = 0; cf < 8; cf++){
        int vrw = cf * 16 + l15;               // h row in sVt; vrw&7 == l15&7
        short8 bv = *(const short8*)(sVt + buf + (vrw << 6)
                                     + ((((kq << 2) | quad) ^ (l15 & 7)) << 3));
        o_acc[rf][cf] = __builtin_amdgcn_mfma_f32_16x16x32_bf16(ap, bv, o_acc[rf][cf], 0, 0, 0);
      }
    }
  }
  // ---- pair-merge the two key-halves (kq=0 -> kq=1) through dead sK/sVt ----
  __syncthreads();                             // all PV reads of sK/sVt done
  float* ex  = (float*)sK;                     // 2 x 16KB  (o_acc halves)
  float* exl = (float*)sVt;                    // 2 x 2KB   (l partials)
  if(kq == 0){
    #pragma unroll
    for(int rf = 0; rf < 2; rf++)
      #pragma unroll
      for(int cf = 0; cf < 8; cf++)
        *(floatx4*)&ex[rq * 4096 + (rf * 8 + cf) * 256 + lane * 4] = o_acc[rf][cf];
    #pragma unroll
    for(int rf = 0; rf < 2; rf++)
      #pragma unroll
      for(int r = 0; r < 4; r++)
        exl[rq * 512 + (rf * 4 + r) * 64 + lane] = l_loc[rf][r];
  }
  __syncthreads();
  if(kq == 1){
    #pragma unroll
    for(int rf = 0; rf < 2; rf++)
      #pragma unroll
      for(int cf = 0; cf < 8; cf++){
        floatx4 o0 = *(const floatx4*)&ex[rq * 4096 + (rf * 8 + cf) * 256 + lane * 4];
        o_acc[rf][cf] += o0;
      }
    #pragma unroll
    for(int rf = 0; rf < 2; rf++){
      #pragma unroll
      for(int r = 0; r < 4; r++){
        float l = l_loc[rf][r] + exl[rq * 512 + (rf * 4 + r) * 64 + lane];
        #pragma unroll
        for(int off = 1; off < 16; off <<= 1) l += __shfl_xor(l, off);
        float invl = 1.f / l;
        long rowe = (long)b * 2048 + qt * 64 + rq * 32 + rf * 16 + quad * 4 + r;
        #pragma unroll
        for(int cf = 0; cf < 8; cf++)
          enc[rowe * 2048 + (kv * 2 + g) * 128 + cf * 16 + l15] = f2b(o_acc[rf][cf][r] * invl);
      }
    }
  }
}

// ---------------------------------------------------------------------------
extern "C" void kernel_launch(void* const* d_in, const int* in_sizes, int n_in,
                              void* d_out, int out_size, void* d_ws, size_t ws_size,
                              hipStream_t stream){
  const float* x     = (const float*)d_in[0];
  const int*   posi  = (const int*)  d_in[1];
  // d_in[2] = attn_mask (causal, known analytically) -- unused
  const float* w_q   = (const float*)d_in[3];
  const float* w_kv  = (const float*)d_in[4];
  const float* w_out = (const float*)d_in[5];
  float* out = (float*)d_out;

  char* w = (char*)d_ws;                        // 74 MB used
  u16* xb     = (u16*)(w);                      // 16 MB (reused as enc after qkv)
  u16* wq_t   = (u16*)(w + 16777216);           //  8 MB [16][128][2048]
  u16* wkv_t  = (u16*)(w + 25165824);           //  8 MB [2][8][128][2048]
  u16* wout_t = (u16*)(w + 33554432);           //  8 MB [2048][2048]
  u16* q_buf  = (u16*)(w + 41943040);           // 16 MB [4096][2048]
  u16* k_buf  = (u16*)(w + 58720256);           //  8 MB [4096][1024]
  u16* v_t    = (u16*)(w + 67108864);           //  8 MB [2][8][128][2048]
  float* tab  = (float*)(w + 75497472);         //  2 MB sin/cos
  u16* enc    = xb;                             // xb dead after qkv

  k_prep    <<<12288, 256, 0, stream>>>(x, xb, w_q, wq_t, w_kv, wkv_t, w_out, wout_t, posi, tab);
  k_gemm_qkv<<<dim3(32, 32), 256, 0, stream>>>(xb, wq_t, wkv_t, tab, q_buf, k_buf, v_t);
  k_flash   <<<dim3(32, 32), 256, 0, stream>>>(q_buf, k_buf, v_t, enc);
  k_gemm_out<<<dim3(32, 16), 256, 0, stream>>>(enc, wout_t, out);
}